// Round 1
// 731.068 us; speedup vs baseline: 1.0327x; 1.0327x over previous
//
#include <hip/hip_runtime.h>
#include <hip/hip_bf16.h>

typedef unsigned short u16;
typedef unsigned int   u32;

using bf16x8 = __attribute__((ext_vector_type(8))) short;  // 8 bf16 (4 VGPRs)
using f32x4  = __attribute__((ext_vector_type(4))) float;  // MFMA accum
using fvec4  = __attribute__((ext_vector_type(4))) float;
using u16x4  = __attribute__((ext_vector_type(4))) unsigned short;

#define BSZ   8192
#define DIN   2048
#define MMD   1600
#define NCH   20
#define CSZ   80
#define DOUT  3000

// ---------- bf16 helpers ----------
__device__ __forceinline__ float bf2f(u16 u) {
    u32 x = ((u32)u) << 16; float f; __builtin_memcpy(&f, &x, 4); return f;
}
__device__ __forceinline__ u16 f2bf(float f) {  // RNE
    u32 x; __builtin_memcpy(&x, &f, 4);
    u32 r = x + 0x7fffu + ((x >> 16) & 1u);
    return (u16)(r >> 16);
}

// ---------- async global->LDS, 16B/lane, wave-uniform LDS base ----------
__device__ __forceinline__ void gl2lds16(const void* g, const void* l) {
    __builtin_amdgcn_global_load_lds(
        (const __attribute__((address_space(1))) u32*)g,
        (__attribute__((address_space(3))) u32*)l, 16, 0, 0);
}

// ---------- converters ----------
__global__ void cast_bf16_k(const float* __restrict__ src, u16* __restrict__ dst, int n4) {
    int i = blockIdx.x * blockDim.x + threadIdx.x;
    if (i < n4) {
        fvec4 v = ((const fvec4*)src)[i];
        u16x4 o;
        o.x = f2bf(v.x); o.y = f2bf(v.y); o.z = f2bf(v.z); o.w = f2bf(v.w);
        ((u16x4*)dst)[i] = o;
    }
}

// src: [K][N] f32 -> dst: [Npad][K] bf16, zero rows for n>=N.
__global__ void transpose_cast_k(const float* __restrict__ src, u16* __restrict__ dst,
                                 int K, int N) {
    __shared__ float t[32][33];
    int k0 = blockIdx.x * 32, n0 = blockIdx.y * 32;
    int tx = threadIdx.x & 31, ty = threadIdx.x >> 5;
#pragma unroll
    for (int r = 0; r < 4; r++) {
        int n = n0 + tx;
        float v = (n < N) ? src[(size_t)(k0 + ty + 8 * r) * N + n] : 0.f;
        t[ty + 8 * r][tx] = v;
    }
    __syncthreads();
#pragma unroll
    for (int r = 0; r < 4; r++)
        dst[(size_t)(n0 + ty + 8 * r) * K + k0 + tx] = f2bf(t[tx][ty + 8 * r]);
}

// ---------- m97-style GEMM with XOR-swizzled LDS (unchanged) ----------
template<bool OUT_BF16>
__global__ __launch_bounds__(256, 2) void gemm_bt_k(
    const u16* __restrict__ A, const u16* __restrict__ BT,
    const float* __restrict__ bias, void* __restrict__ C, int K, int N) {
    __shared__ __align__(16) u16 As[128 * 64];
    __shared__ __align__(16) u16 Bs[128 * 64];
    const int tid = threadIdx.x, w = tid >> 6, lane = tid & 63;
    const int lr = lane & 15, lk = lane >> 4, s7 = lr & 7;
    const int m0 = blockIdx.x * 128, n0 = blockIdx.y * 128;
    const int mh = (w >> 1) * 64, nh = (w & 1) * 64;
    const int so = (lane & 7) ^ (lane >> 3);
    int arow[4], brow[4];
#pragma unroll
    for (int i = 0; i < 4; i++) { arow[i] = (mh + i * 16 + lr) * 64; brow[i] = (nh + i * 16 + lr) * 64; }
    f32x4 acc[4][4] = {};
    const u16* Ag = A + (size_t)m0 * K;
    const u16* Bg = BT + (size_t)n0 * K;
    const int nslab = K >> 6;
    for (int kt = 0; kt < nslab; ++kt) {
        const int k0 = kt * 64;
        __syncthreads();
#pragma unroll
        for (int q = 0; q < 4; q++) {
            int ch = w * 4 + q;
            int row = ch * 8 + (lane >> 3);
            gl2lds16(Ag + (size_t)row * K + k0 + so * 8, As + ch * 512);
            gl2lds16(Bg + (size_t)row * K + k0 + so * 8, Bs + ch * 512);
        }
        __syncthreads();
#pragma unroll
        for (int ks = 0; ks < 64; ks += 32) {
            const int px = (((ks >> 3) + lk) ^ s7) * 8;
            bf16x8 av[4], bv[4];
#pragma unroll
            for (int i = 0; i < 4; i++) av[i] = *(const bf16x8*)(As + arow[i] + px);
#pragma unroll
            for (int j = 0; j < 4; j++) bv[j] = *(const bf16x8*)(Bs + brow[j] + px);
#pragma unroll
            for (int i = 0; i < 4; i++)
#pragma unroll
                for (int j = 0; j < 4; j++)
                    acc[i][j] = __builtin_amdgcn_mfma_f32_16x16x32_bf16(av[i], bv[j], acc[i][j], 0, 0, 0);
        }
    }
#pragma unroll
    for (int j = 0; j < 4; j++) {
        int n = n0 + nh + j * 16 + lr;
        if (n < N) {
            float bv = bias[n];
#pragma unroll
            for (int i = 0; i < 4; i++) {
                int mb = m0 + mh + i * 16 + lk * 4;
#pragma unroll
                for (int r = 0; r < 4; r++) {
                    float v = acc[i][j][r] + bv;
                    if (OUT_BF16) ((u16*)C)[(size_t)(mb + r) * N + n] = f2bf(v);
                    else          ((float*)C)[(size_t)(mb + r) * N + n] = v;
                }
            }
        }
    }
}

// ---------- bilinear, v2 ----------
// z = sum_s h0[:,s] * (h1 @ Wb[c,:,s,:]^T).
// Changes vs v1:
//  * A fragments (h1) are s-invariant -> hoisted to 6 bf16x8 registers, loaded
//    once straight from global. h1 LDS tile removed entirely.
//  * Ws rows padded 96 -> 104 u16 (52 dw = 20 mod 32 banks): ds_read_b128
//    across lr-lanes spreads over all 8 bank-quads -> 2-way (free) vs 8-way.
//  * Ws triple-buffered, ONE raw s_barrier per s with counted
//    s_waitcnt vmcnt(12): this iteration's 4-5 gl2lds + 8 h0 loads stay in
//    flight; everything older (the buffer being read) is retired. h0 scalars
//    software-pipelined one s ahead so the wait never sits on them.
//    Race-freedom: stage(s+1) writes buf[(s+1)%3]; concurrent reads in the
//    same inter-barrier window are buf[(s-1)%3]; 2 mod 3 != 0.
__global__ __launch_bounds__(256, 2) void bilinear_k(
    const u16* __restrict__ h0g, const u16* __restrict__ h1g,
    const u16* __restrict__ Wbg, const float* __restrict__ bbg,
    u16* __restrict__ zg) {
    constexpr int WROW = 104;             // u16 per Ws row (13 octets)
    constexpr int WBUF = CSZ * WROW;      // 8320 u16 per buffer
    __shared__ __align__(16) u16 Ws[3 * WBUF];   // 49920 B
    const int tid = threadIdx.x, w = tid >> 6, lane = tid & 63;
    const int lr = lane & 15, lk = lane >> 4;
    const int m0 = blockIdx.x * 128, c = blockIdx.y;

    // zero pad octets (t = 80..95) of every row, all 3 buffers (480 stores)
#pragma unroll
    for (int t = 0; t < 2; ++t) {
        int q = t * 256 + tid;
        if (q < 480) {
            int b = q / 160, r2 = q - b * 160;
            *(fvec4*)(Ws + b * WBUF + (r2 >> 1) * WROW + 80 + (r2 & 1) * 8) =
                (fvec4){0.f, 0.f, 0.f, 0.f};
        }
    }

    // Ws staging descriptors: 1040 octet-positions (80 rows x 13), real o<10
    const u16* WgBase = Wbg + (size_t)c * CSZ * 6400;
    const u16* wsrc[5];
    bool wok[5];
    int wdst[5];
#pragma unroll
    for (int it = 0; it < 5; ++it) {
        int p = it * 256 + tid;
        int row = p / 13, o = p - row * 13;
        wok[it] = (p < 1040) && (o < 10);
        wsrc[it] = WgBase + (size_t)row * 6400 + o * 8;  // +80 per s
        wdst[it] = (it * 256 + w * 64) * 8;
    }

    // h0 scalar gather offsets (per-lane rows, column advances with s)
    const u16* hbase = h0g + (size_t)m0 * MMD + c * CSZ;
    int hoff[8];
#pragma unroll
    for (int i = 0; i < 2; ++i)
#pragma unroll
        for (int r = 0; r < 4; ++r)
            hoff[i * 4 + r] = (w * 32 + i * 16 + lk * 4 + r) * MMD;

    // prologue: stage buf0 (s=0), h0 for s=0
#pragma unroll
    for (int it = 0; it < 5; ++it) {
        if (wok[it]) gl2lds16(wsrc[it], Ws + wdst[it]);
        wsrc[it] += CSZ;
    }
    u16 h0r[8];
#pragma unroll
    for (int k = 0; k < 8; ++k) h0r[k] = hbase[hoff[k]];
    const u16* hs = hbase + 1;

    // hoist A fragments (s-invariant) straight from global; zero the k>=80 pad
    bf16x8 av[2][3];
    const u16* h1base = h1g + (size_t)m0 * MMD + c * CSZ;
#pragma unroll
    for (int i = 0; i < 2; ++i) {
        const u16* rowp = h1base + (size_t)(w * 32 + i * 16 + lr) * MMD;
#pragma unroll
        for (int st = 0; st < 3; ++st) {
            if (st == 2 && lk >= 2) {
                av[i][st] = (bf16x8){0, 0, 0, 0, 0, 0, 0, 0};
            } else {
                av[i][st] = *(const bf16x8*)(rowp + st * 32 + lk * 8);
            }
        }
    }

    __syncthreads();   // full drain: pads + buf0 + av + h0r all resolved

    int boff[5];
#pragma unroll
    for (int j = 0; j < 5; ++j) boff[j] = (j * 16 + lr) * WROW + lk * 8;

    f32x4 z[2][5] = {};
    const f32x4 zf = {0.f, 0.f, 0.f, 0.f};
    int bufR = 0, bufW = 1;
#pragma unroll 1
    for (int s = 0; s < 80; ++s) {
        u16 h0n[8];
        if (s < 79) {
            // stage s+1 into bufW (4-5 gl2lds per wave)
#pragma unroll
            for (int it = 0; it < 5; ++it) {
                if (wok[it]) gl2lds16(wsrc[it], Ws + bufW * WBUF + wdst[it]);
                wsrc[it] += CSZ;
            }
            // h0 for s+1 (8 scalar loads, consumed NEXT iteration)
#pragma unroll
            for (int k = 0; k < 8; ++k) h0n[k] = hs[hoff[k]];
            hs += 1;
            // retire everything older than this iteration's 12-13 VMEM ops:
            // i.e. the staging of bufR (issued last iteration) has landed.
            asm volatile("s_waitcnt vmcnt(12)" ::: "memory");
        } else {
            asm volatile("s_waitcnt vmcnt(0)" ::: "memory");
        }
        __builtin_amdgcn_s_barrier();
        asm volatile("" ::: "memory");  // keep ds_reads below the barrier

        const u16* Wr = Ws + bufR * WBUF;
        f32x4 P[2][5];
#pragma unroll
        for (int st = 0; st < 3; ++st) {
            bf16x8 bv[5];
#pragma unroll
            for (int j = 0; j < 5; ++j) bv[j] = *(const bf16x8*)(Wr + boff[j] + st * 32);
#pragma unroll
            for (int i = 0; i < 2; ++i)
#pragma unroll
                for (int j = 0; j < 5; ++j)
                    P[i][j] = __builtin_amdgcn_mfma_f32_16x16x32_bf16(
                        av[i][st], bv[j], st == 0 ? zf : P[i][j], 0, 0, 0);
        }
#pragma unroll
        for (int i = 0; i < 2; ++i)
#pragma unroll
            for (int r = 0; r < 4; ++r) {
                float h0f = bf2f(h0r[i * 4 + r]);
#pragma unroll
                for (int j = 0; j < 5; ++j)
                    z[i][j][r] += h0f * P[i][j][r];
            }
        if (s < 79) {
#pragma unroll
            for (int k = 0; k < 8; ++k) h0r[k] = h0n[k];
        }
        bufR = (bufR == 2) ? 0 : bufR + 1;
        bufW = (bufW == 2) ? 0 : bufW + 1;
    }

    // epilogue: +bb, signed sqrt, per-row L2 norm over the 80 chunk cols
    float bbv[5];
#pragma unroll
    for (int j = 0; j < 5; j++) bbv[j] = bbg[c * CSZ + j * 16 + lr];
    float sq[2][4] = {};
#pragma unroll
    for (int i = 0; i < 2; i++)
#pragma unroll
        for (int j = 0; j < 5; j++)
#pragma unroll
            for (int r = 0; r < 4; r++) {
                float v = z[i][j][r] + bbv[j];
                float a = sqrtf(fabsf(v));
                v = (v < 0.f) ? -a : a;
                z[i][j][r] = v;
                sq[i][r] += v * v;
            }
#pragma unroll
    for (int d = 1; d < 16; d <<= 1)
#pragma unroll
        for (int i = 0; i < 2; i++)
#pragma unroll
            for (int r = 0; r < 4; r++)
                sq[i][r] += __shfl_xor(sq[i][r], d, 64);
    float sc[2][4];
#pragma unroll
    for (int i = 0; i < 2; i++)
#pragma unroll
        for (int r = 0; r < 4; r++)
            sc[i][r] = 1.f / fmaxf(sqrtf(sq[i][r]), 1e-12f);
#pragma unroll
    for (int i = 0; i < 2; i++)
#pragma unroll
        for (int r = 0; r < 4; r++) {
            int row = m0 + w * 32 + i * 16 + lk * 4 + r;
#pragma unroll
            for (int j = 0; j < 5; j++) {
                int col = c * CSZ + j * 16 + lr;
                zg[(size_t)row * MMD + col] = f2bf(z[i][j][r] * sc[i][r]);
            }
        }
}

// ---------- launcher ----------
extern "C" void kernel_launch(void* const* d_in, const int* in_sizes, int n_in,
                              void* d_out, int out_size, void* d_ws, size_t ws_size,
                              hipStream_t stream) {
    (void)in_sizes; (void)n_in; (void)out_size; (void)ws_size;
    const float* x0 = (const float*)d_in[0];
    const float* x1 = (const float*)d_in[1];
    const float* W0 = (const float*)d_in[2];
    const float* b0 = (const float*)d_in[3];
    const float* W1 = (const float*)d_in[4];
    const float* b1 = (const float*)d_in[5];
    const float* Wb = (const float*)d_in[6];
    const float* bb = (const float*)d_in[7];
    const float* Wo = (const float*)d_in[8];
    const float* bo = (const float*)d_in[9];

    char* ws = (char*)d_ws;
    size_t off = 0;
    auto alloc = [&](size_t bytes) { void* p = ws + off; off += (bytes + 255) & ~(size_t)255; return p; };
    u16* x0b = (u16*)alloc((size_t)BSZ * DIN * 2);
    u16* x1b = (u16*)alloc((size_t)BSZ * DIN * 2);
    u16* W0T = (u16*)alloc((size_t)1664 * DIN * 2);
    u16* W1T = (u16*)alloc((size_t)1664 * DIN * 2);
    u16* WbB = (u16*)alloc((size_t)NCH * CSZ * 6400 * 2);
    u16* WoT = (u16*)alloc((size_t)3072 * MMD * 2);
    u16* h0  = (u16*)alloc((size_t)BSZ * MMD * 2);
    u16* h1  = (u16*)alloc((size_t)BSZ * MMD * 2);
    u16* z   = x0b;  // alias: x0b dead after first GEMM

    cast_bf16_k<<<dim3(16384), dim3(256), 0, stream>>>(x0, x0b, (BSZ * DIN) / 4);
    cast_bf16_k<<<dim3(16384), dim3(256), 0, stream>>>(x1, x1b, (BSZ * DIN) / 4);
    cast_bf16_k<<<dim3(10000), dim3(256), 0, stream>>>(Wb, WbB, (NCH * CSZ * 6400) / 4);
    transpose_cast_k<<<dim3(DIN / 32, 1664 / 32), dim3(256), 0, stream>>>(W0, W0T, DIN, MMD);
    transpose_cast_k<<<dim3(DIN / 32, 1664 / 32), dim3(256), 0, stream>>>(W1, W1T, DIN, MMD);
    transpose_cast_k<<<dim3(MMD / 32, 3072 / 32), dim3(256), 0, stream>>>(Wo, WoT, MMD, DOUT);
    gemm_bt_k<true><<<dim3(BSZ / 128, 13), dim3(256), 0, stream>>>(x0b, W0T, b0, h0, DIN, MMD);
    gemm_bt_k<true><<<dim3(BSZ / 128, 13), dim3(256), 0, stream>>>(x1b, W1T, b1, h1, DIN, MMD);
    bilinear_k<<<dim3(BSZ / 128, NCH), dim3(256), 0, stream>>>(h0, h1, WbB, bb, z);
    gemm_bt_k<false><<<dim3(BSZ / 128, 24), dim3(256), 0, stream>>>(z, WoT, bo, d_out, MMD, DOUT);
}